// Round 8
// baseline (150125.330 us; speedup 1.0000x reference)
//
#include <hip/hip_runtime.h>
#include <stdint.h>

typedef unsigned short u16;

#define T_STEPS 512
#define BATCH   64
#define DIN     512
#define HID     1024
#define G4      4096
#define THREADS 512
#define NXCD    8
#define BPX     32      // blocks (ranks) per XCD
#define ROWS    8       // batch rows per XCD
#define UPB     32      // hidden units per block

// LDS map (bytes)
#define LDS_W    0              // u16 [64 kb][128 c][8]  = 131072
#define LDS_HA   131072         // u16 [128 kb][8 row][8] = 16384
#define LDS_Z    147456         // f32 [8 wave][8 row][16] = 4096
#define LDS_HOUT 151552         // u16 [4 kb][8 row][8]   = 512
#define SM_BYTES 152064         // forces 1 block/CU -> exactly 32 blocks/XCD

// ws map
#define XB_BYTES   ((size_t)T_STEPS * BATCH * DIN * 2)   // 32 MB bf16 x
#define HBX_OFF    XB_BYTES
#define HBX_STRIDE 65536        // per-XCD region (2 bufs x 16KB + pad)
#define HBUF_SZ    16384
#define FLG_OFF    (HBX_OFF + (size_t)NXCD * HBX_STRIDE)
#define FLG_STRIDE 4096
#define CTR_OFF    (FLG_OFF + (size_t)NXCD * FLG_STRIDE)
#define WS_NEED    (CTR_OFF + (size_t)NXCD * 64)

typedef float f32x4 __attribute__((ext_vector_type(4)));
typedef short bf16x8 __attribute__((ext_vector_type(8)));
typedef unsigned uint32x4 __attribute__((ext_vector_type(4)));

__device__ __forceinline__ u16 f2bf(float f) {
  unsigned u = __float_as_uint(f);
  u += 0x7fffu + ((u >> 16) & 1u);   // RNE
  return (u16)(u >> 16);
}
__device__ __forceinline__ float sigm(float x) {
  return __builtin_amdgcn_rcpf(1.f + __expf(-x));
}
__device__ __forceinline__ float fast_tanh(float x) {
  return 1.f - 2.f * __builtin_amdgcn_rcpf(__expf(2.f * x) + 1.f);
}

// sc0 = bypass L1, served by the local XCD L2 (intra-XCD coherent).
__device__ __forceinline__ uint32x4 load16_sc0(uint64_t addr) {
  uint32x4 d;
  asm volatile("global_load_dwordx4 %0, %1, off sc0" : "=v"(d) : "v"(addr));
  return d;
}
__device__ __forceinline__ unsigned load4_sc0(uint64_t addr) {
  unsigned d;
  asm volatile("global_load_dword %0, %1, off sc0" : "=v"(d) : "v"(addr));
  return d;
}
__device__ __forceinline__ void store16_sc0(uint64_t addr, uint32x4 v) {
  asm volatile("global_store_dwordx4 %0, %1, off sc0" :: "v"(addr), "v"(v) : "memory");
}
__device__ __forceinline__ void store4_sc0(uint64_t addr, unsigned v) {
  asm volatile("global_store_dword %0, %1, off sc0" :: "v"(addr), "v"(v) : "memory");
}
#define WAITV(n) asm volatile("s_waitcnt vmcnt(" #n ")" ::: "memory")

// x[B][T][D] fp32 -> xb[T][B][D] bf16
__global__ void cvt_x(const float* __restrict__ x, u16* __restrict__ xb) {
  int i = blockIdx.x * 256 + threadIdx.x;
  int dblk = i & 63;
  int rest = i >> 6;
  int b = rest & 63;
  int t = rest >> 6;
  const float4* s = reinterpret_cast<const float4*>(x + ((size_t)(b * T_STEPS + t)) * DIN + dblk * 8);
  float4 f0 = s[0], f1 = s[1];
  uint4 o;
  o.x = (unsigned)f2bf(f0.x) | ((unsigned)f2bf(f0.y) << 16);
  o.y = (unsigned)f2bf(f0.z) | ((unsigned)f2bf(f0.w) << 16);
  o.z = (unsigned)f2bf(f1.x) | ((unsigned)f2bf(f1.y) << 16);
  o.w = (unsigned)f2bf(f1.z) | ((unsigned)f2bf(f1.w) << 16);
  *reinterpret_cast<uint4*>(xb + ((size_t)(t * BATCH + b)) * DIN + dblk * 8) = o;
}

// Batch-partitioned persistent LSTM: XCD g owns batch rows [g*8, g*8+8);
// its 32 blocks (rank 0..31 via local election) each own 32 hidden units.
// ALL h exchange is XCD-local through the XCD's own L2 (sc0) -- no cross-XCD
// traffic in the loop. Col layout c = u_local*4 + gate so each wave's 16-col
// N-tile holds 4 complete units -> gates computed wave-locally, no z-reduction.
// MFMA M=16 with 8 real rows (rows 8..15 duplicate rows 0..7, results ignored).
__launch_bounds__(THREADS, 2)
__global__ void lstm_kernel(const float* __restrict__ W, const float* __restrict__ U,
                            const float* __restrict__ bias, char* __restrict__ ws,
                            float* __restrict__ out) {
  __shared__ __align__(16) char sm[SM_BYTES];
  __shared__ int s_xcd, s_rank;
  u16* Wlds   = (u16*)(sm + LDS_W);
  u16* hA     = (u16*)(sm + LDS_HA);
  float* zscr = (float*)(sm + LDS_Z);
  u16* hout   = (u16*)(sm + LDS_HOUT);

  const int tid = threadIdx.x;
  if (tid == 0) {
    unsigned xr;
    asm volatile("s_getreg_b32 %0, hwreg(HW_REG_XCC_ID)" : "=s"(xr));
    int g = (int)(xr & (NXCD - 1));
    s_xcd = g;
    unsigned* ctr = (unsigned*)(ws + CTR_OFF + (size_t)g * 64);
    s_rank = (int)atomicAdd(ctr, 1u);
  }
  __syncthreads();
  const int g = s_xcd;
  const int rank = s_rank;
  if (rank >= BPX) return;   // impossible with 1 block/CU; safety

  const int l    = tid & 63;
  const int wv   = tid >> 6;            // N-tile 0..7
  const int q    = l >> 4;              // k quarter
  const int row8 = l & 7;               // A-row (rows 8..15 duplicate 0..7)
  const int c16  = l & 15;
  const int colB = wv * 16 + c16;       // block-local col 0..127
  const int gcolB = ((colB & 3) << 10) + rank * UPB + (colB >> 2);

  // ---- init: stage W slice into LDS: Wlds[kb][c][i] = W[kb*8+i][gcol(c)] ----
  for (int idx = tid; idx < 64 * 128; idx += THREADS) {
    int kb = idx >> 7, c = idx & 127;
    int gcol = ((c & 3) << 10) + rank * UPB + (c >> 2);
    bf16x8 v;
#pragma unroll
    for (int i = 0; i < 8; ++i)
      v[i] = (short)f2bf(W[(size_t)(kb * 8 + i) * G4 + gcol]);
    *(bf16x8*)(Wlds + idx * 8) = v;
  }

  // ---- init: U fragments -> registers (128 VGPR) ----
  bf16x8 ubf[32];
#pragma unroll
  for (int kt = 0; kt < 32; ++kt) {
    bf16x8 v;
#pragma unroll
    for (int i = 0; i < 8; ++i)
      v[i] = (short)f2bf(U[(size_t)(kt * 32 + q * 8 + i) * G4 + gcolB]);
    ubf[kt] = v;
  }

  // gate-lane constants (lanes < 32): lane -> (batch b_g, unit uu of this wave)
  const int b_g = l >> 2;
  const int uu  = wv * 4 + (l & 3);
  const int j   = rank * UPB + uu;
  const float bi  = bias[j];
  const float bf_ = bias[1024 + j];
  const float bg  = bias[2048 + j];
  const float bo  = bias[3072 + j];

  const u16* xb = (const u16*)ws;
  const uint64_t hbase = (uint64_t)ws + HBX_OFF + (uint64_t)g * HBX_STRIDE;
  const uint64_t fb    = (uint64_t)ws + FLG_OFF + (uint64_t)g * FLG_STRIDE;
  const uint64_t faddr = fb + (uint64_t)(l & 31) * 16;

  float c_reg = 0.f;
  int alive = 1;

  __syncthreads();   // Wlds staged

  for (int t = 0; t < T_STEPS; ++t) {
    f32x4 acc = {0.f, 0.f, 0.f, 0.f};

    // ---- x_t @ W (h-independent overlap; plain cached loads, L1 absorbs) ----
    const u16* xa = xb + ((size_t)t * BATCH + g * ROWS + row8) * DIN + q * 8;
#pragma unroll
    for (int kt = 0; kt < 16; ++kt) {
      bf16x8 wf = *(const bf16x8*)(Wlds + ((kt * 4 + q) * 128 + colB) * 8);
      bf16x8 xv = *(const bf16x8*)(xa + kt * 32);
      acc = __builtin_amdgcn_mfma_f32_16x16x32_bf16(xv, wf, acc, 0, 0, 0);
    }

    // ---- poll 32 XCD-local flags (sc0, own-L2; bounded -> no hangs ever) ----
    if (alive) {
      int spins = 0;
      while (true) {
        unsigned f = load4_sc0(faddr);
        WAITV(0);
        if (__all(f >= (unsigned)t)) break;
        if (++spins > (1 << 20)) { alive = 0; break; }
        __builtin_amdgcn_s_sleep(2);
      }
    }

    // ---- stage h_t (16KB) into LDS cooperatively ----
    {
      const uint64_t src = hbase + (uint64_t)(t & 1) * HBUF_SZ + (uint64_t)tid * 32;
      uint32x4 a0 = load16_sc0(src);
      uint32x4 a1 = load16_sc0(src + 16);
      WAITV(0);
      *(uint32x4*)(hA + tid * 16)     = a0;
      *(uint32x4*)(hA + tid * 16 + 8) = a1;
    }
    __syncthreads();

    // ---- h_t @ U ----
#pragma unroll
    for (int kt = 0; kt < 32; ++kt) {
      bf16x8 av = *(const bf16x8*)(hA + ((kt * 4 + q) * 8 + row8) * 8);
      acc = __builtin_amdgcn_mfma_f32_16x16x32_bf16(av, ubf[kt], acc, 0, 0, 0);
    }

    // ---- z -> per-wave LDS scratch (real rows 0..7 only; C row = q*4+reg) ----
    if (q < 2) {
#pragma unroll
      for (int r = 0; r < 4; ++r)
        zscr[wv * 128 + (q * 4 + r) * 16 + c16] = acc[r];
    }
    asm volatile("s_waitcnt lgkmcnt(0)" ::: "memory");
    __builtin_amdgcn_sched_barrier(0);

    // ---- gates: lanes < 32 handle (batch, unit); 4 gates are 16B contiguous ----
    if (l < 32) {
      const float* zr = &zscr[wv * 128 + b_g * 16 + (l & 3) * 4];
      float zi = zr[0] + bi, zf = zr[1] + bf_, zg = zr[2] + bg, zo = zr[3] + bo;
      float ig = sigm(zi), fg = sigm(zf), og = sigm(zo);
      float gg = fast_tanh(zg);
      c_reg = fg * c_reg + ig * gg;
      float h = og * fast_tanh(c_reg);
      hout[(uu >> 3) * 64 + b_g * 8 + (uu & 7)] = f2bf(h);
      if (t == T_STEPS - 1) {
        float* orow = out + (size_t)(g * ROWS + b_g) * 3072 + j;
        orow[0]    = h;       // h_T
        orow[1024] = h;       // h_T again
        orow[2048] = c_reg;   // c_T
      }
    }
    __syncthreads();   // hout complete; hA reads done

    // ---- publish h_{t+1} slice (512B) + flag: wave 0, sc0 into own L2 ----
    if (wv == 0 && l < 32) {
      uint32x4 hv = *(const uint32x4*)(hout + l * 8);
      uint64_t dst = hbase + (uint64_t)((t + 1) & 1) * HBUF_SZ +
                     (uint64_t)((rank * 4 + (l >> 3)) * 8 + (l & 7)) * 16;
      store16_sc0(dst, hv);
      WAITV(0);
      if (l == 0) store4_sc0(fb + (uint64_t)rank * 16, (unsigned)(t + 1));
    }
  }
}

extern "C" void kernel_launch(void* const* d_in, const int* in_sizes, int n_in,
                              void* d_out, int out_size, void* d_ws, size_t ws_size,
                              hipStream_t stream) {
  const float* x = (const float*)d_in[0];
  const float* W = (const float*)d_in[1];
  const float* U = (const float*)d_in[2];
  const float* b = (const float*)d_in[3];
  float* out = (float*)d_out;

  if (ws_size < WS_NEED) return;  // loud failure: output stays poisoned

  u16* xb = (u16*)d_ws;
  // zero h buffers + flags + election counters (replayed every graph launch)
  hipMemsetAsync((char*)d_ws + HBX_OFF, 0, WS_NEED - HBX_OFF, stream);
  cvt_x<<<(T_STEPS * BATCH * DIN / 8 + 255) / 256, 256, 0, stream>>>(x, xb);
  lstm_kernel<<<NXCD * BPX, THREADS, 0, stream>>>(W, U, b, (char*)d_ws, out);
}

// Round 9
// 2778.363 us; speedup vs baseline: 54.0337x; 54.0337x over previous
//
#include <hip/hip_runtime.h>
#include <stdint.h>

typedef unsigned short u16;

#define T_STEPS 512
#define BATCH   64
#define DIN     512
#define HID     1024
#define G4      4096
#define THREADS 512
#define GRPS    2       // batch groups (32 rows each)
#define NBG     64      // blocks per group
#define UPB     16      // hidden units per block
// block (grp, nb): rows [grp*32, grp*32+32), units [nb*16, nb*16+16)
// gate-col layout: block-local col c = u_local*4 + gate, gcol = gate*1024 + nb*16 + u_local

#define U_LD    1032    // 1024 + 8 pad (init staging)
#define W_LD    520     // 512 + 8 pad

// LDS: init stage[32][U_LD] = 66048B (W phase 33280B aliased)
//      run  zpart f32[4][32][69] = 35328B @0, hstage u16[512] = 1024B @35328
#define SM_BYTES 66048
#define HS_OFF   35328

// ws map
#define XB_BYTES ((size_t)T_STEPS * BATCH * DIN * 2)   // 32 MB bf16 x
#define HB_OFF   XB_BYTES                              // h: [grp][parity][64KB]
#define HB_GRP   (2u * 32 * HID * 2)                   // 128KB per group
#define FLG_OFF  (HB_OFF + (size_t)GRPS * HB_GRP)
#define FLG_GRP  1024                                  // 64 flags x 16B
#define WS_NEED  (FLG_OFF + (size_t)GRPS * FLG_GRP)

typedef float f32x16 __attribute__((ext_vector_type(16)));
typedef short bf16x8 __attribute__((ext_vector_type(8)));
typedef unsigned uint32x4 __attribute__((ext_vector_type(4)));

__device__ __forceinline__ u16 f2bf(float f) {
  unsigned u = __float_as_uint(f);
  u += 0x7fffu + ((u >> 16) & 1u);   // RNE
  return (u16)(u >> 16);
}
__device__ __forceinline__ float sigm(float x) {
  return __builtin_amdgcn_rcpf(1.f + __expf(-x));
}
__device__ __forceinline__ float fast_tanh(float x) {
  return 1.f - 2.f * __builtin_amdgcn_rcpf(__expf(2.f * x) + 1.f);
}

// Coherent (L2-bypass, served at the coherence point) helpers; flat 64b addr.
__device__ __forceinline__ uint32x4 load16_sc(uint64_t addr) {
  uint32x4 d;
  asm volatile("global_load_dwordx4 %0, %1, off sc0 sc1" : "=v"(d) : "v"(addr));
  return d;
}
__device__ __forceinline__ unsigned load4_sc(uint64_t addr) {
  unsigned d;
  asm volatile("global_load_dword %0, %1, off sc0 sc1" : "=v"(d) : "v"(addr));
  return d;
}
__device__ __forceinline__ void store16_sc(uint64_t addr, uint32x4 v) {
  asm volatile("global_store_dwordx4 %0, %1, off sc0 sc1" :: "v"(addr), "v"(v) : "memory");
}
__device__ __forceinline__ void store4_sc(uint64_t addr, unsigned v) {
  asm volatile("global_store_dword %0, %1, off sc0 sc1" :: "v"(addr), "v"(v) : "memory");
}
#define WAITV(n) asm volatile("s_waitcnt vmcnt(" #n ")" ::: "memory")

// x[B][T][D] fp32 -> xb[T][B][D] bf16
__global__ void cvt_x(const float* __restrict__ x, u16* __restrict__ xb) {
  int i = blockIdx.x * 256 + threadIdx.x;
  int dblk = i & 63;
  int rest = i >> 6;
  int b = rest & 63;
  int t = rest >> 6;
  const float4* s = reinterpret_cast<const float4*>(x + ((size_t)(b * T_STEPS + t)) * DIN + dblk * 8);
  float4 f0 = s[0], f1 = s[1];
  uint4 o;
  o.x = (unsigned)f2bf(f0.x) | ((unsigned)f2bf(f0.y) << 16);
  o.y = (unsigned)f2bf(f0.z) | ((unsigned)f2bf(f0.w) << 16);
  o.z = (unsigned)f2bf(f1.x) | ((unsigned)f2bf(f1.y) << 16);
  o.w = (unsigned)f2bf(f1.z) | ((unsigned)f2bf(f1.w) << 16);
  *reinterpret_cast<uint4*>(xb + ((size_t)(t * BATCH + b)) * DIN + dblk * 8) = o;
}

// Persistent LSTM, 2 independent batch-groups x 64 col-blocks.
// GEMM per block: M=32 rows, N=64 gate-cols, K=1536; 32x32x16 MFMA;
// 8 waves = 2 N-tiles x 4 K-splits; B-frags in registers; partials via LDS.
// h layout per group: [parity][kblk=128][row=32][8 units] bf16 (block nb owns
// kblks {2nb, 2nb+1} = contiguous 1KB). Waves poll only their 16 producers.
__launch_bounds__(THREADS)
__global__ void lstm_kernel(const float* __restrict__ W, const float* __restrict__ U,
                            const float* __restrict__ bias, char* __restrict__ ws,
                            float* __restrict__ out) {
  __shared__ __align__(16) char sm[SM_BYTES];
  u16* stage  = (u16*)sm;                 // init staging
  float* zp   = (float*)sm;               // run: [4][32][69]
  u16* hstage = (u16*)(sm + HS_OFF);      // run: [2][32][8] u16

  const int tid = threadIdx.x;
  const int bid = blockIdx.x;
  const int nb  = bid & 63;
  const int grp = bid >> 6;

  const int l    = tid & 63;
  const int wv   = tid >> 6;
  const int n_t  = wv & 1;           // N-tile (32 cols)
  const int ks   = wv >> 1;          // K-split 0..3
  const int cl   = l & 31;           // A-row / B-col within tile
  const int q    = l >> 5;           // k-half of fragment

  // ---- init: 4 staged phases (U lo/hi cols, W lo/hi cols) ----
  bf16x8 ubf[16], wbf[8];
#pragma unroll
  for (int ph = 0; ph < 2; ++ph) {
    for (int idx = tid; idx < 32 * HID; idx += THREADS) {
      int cc = idx & 31, k = idx >> 5;
      int c = ph * 32 + cc;
      int gcol = ((c & 3) << 10) + nb * UPB + (c >> 2);
      stage[cc * U_LD + k] = f2bf(U[(size_t)k * G4 + gcol]);
    }
    __syncthreads();
    if (n_t == ph) {
      const u16* ub = stage + cl * U_LD + ks * 256 + q * 8;
#pragma unroll
      for (int s = 0; s < 16; ++s) ubf[s] = *(const bf16x8*)(ub + s * 16);
    }
    __syncthreads();
  }
#pragma unroll
  for (int ph = 0; ph < 2; ++ph) {
    for (int idx = tid; idx < 32 * DIN; idx += THREADS) {
      int cc = idx & 31, k = idx >> 5;
      int c = ph * 32 + cc;
      int gcol = ((c & 3) << 10) + nb * UPB + (c >> 2);
      stage[cc * W_LD + k] = f2bf(W[(size_t)k * G4 + gcol]);
    }
    __syncthreads();
    if (n_t == ph) {
      const u16* wb = stage + cl * W_LD + ks * 128 + q * 8;
#pragma unroll
      for (int s = 0; s < 8; ++s) wbf[s] = *(const bf16x8*)(wb + s * 16);
    }
    __syncthreads();
  }

  // gate-thread mapping: (row pb, unit pu)
  const int pb = tid & 31;
  const int pu = tid >> 5;           // 0..15
  const int j  = nb * UPB + pu;
  float c_reg = 0.f;
  const float bi  = bias[j];
  const float bf_ = bias[1024 + j];
  const float bg  = bias[2048 + j];
  const float bo  = bias[3072 + j];

  const u16* xb = (const u16*)ws;
  const uint64_t hgrp = (uint64_t)ws + HB_OFF + (uint64_t)grp * HB_GRP;
  const uint64_t fgrp = (uint64_t)ws + FLG_OFF + (uint64_t)grp * FLG_GRP;
  // wave ks consumes kblks [ks*32, ks*32+32) -> producer blocks [ks*16, ks*16+16)
  const uint64_t faddr = fgrp + (uint64_t)(ks * 16 + (l & 15)) * 16;
  // lane h base: kblk = ks*32 + s*2 + q, byte = kblk*512 + cl*16
  const uint64_t hlane = (uint64_t)(ks * 32 + q) * 512 + (uint64_t)cl * 16;

#define HMFMA(S) acc = __builtin_amdgcn_mfma_f32_32x32x16_bf16( \
    __builtin_bit_cast(bf16x8, abuf[S]), ubf[S], acc, 0, 0, 0)

  for (int t = 0; t < T_STEPS; ++t) {
    f32x16 acc = {0.f,0.f,0.f,0.f,0.f,0.f,0.f,0.f,0.f,0.f,0.f,0.f,0.f,0.f,0.f,0.f};

    // ---- x_t @ W (group rows only; plain cached loads; overlaps the wait) ----
    const u16* xa = xb + ((size_t)t * BATCH + grp * 32 + cl) * DIN + ks * 128 + q * 8;
#pragma unroll
    for (int s = 0; s < 8; ++s) {
      bf16x8 xv = *(const bf16x8*)(xa + s * 16);
      acc = __builtin_amdgcn_mfma_f32_32x32x16_bf16(xv, wbf[s], acc, 0, 0, 0);
    }

    // ---- fine-grained poll: this wave's 16 producers only ----
    while (true) {
      unsigned f = load4_sc(faddr);
      WAITV(0);
      if (__all(f >= (unsigned)t)) break;
      __builtin_amdgcn_s_sleep(1);
    }

    // ---- h_t @ U: 16 sc1 loads in flight, counted vmcnt ----
    const uint64_t hb = hgrp + (uint64_t)(t & 1) * 65536 + hlane;
    uint32x4 abuf[16];
#pragma unroll
    for (int s = 0; s < 16; ++s) abuf[s] = load16_sc(hb + (uint64_t)s * 1024);
    WAITV(12); __builtin_amdgcn_sched_barrier(0);
    HMFMA(0); HMFMA(1); HMFMA(2); HMFMA(3);
    WAITV(8); __builtin_amdgcn_sched_barrier(0);
    HMFMA(4); HMFMA(5); HMFMA(6); HMFMA(7);
    WAITV(4); __builtin_amdgcn_sched_barrier(0);
    HMFMA(8); HMFMA(9); HMFMA(10); HMFMA(11);
    WAITV(0); __builtin_amdgcn_sched_barrier(0);
    HMFMA(12); HMFMA(13); HMFMA(14); HMFMA(15);

    // ---- K-split partial -> LDS (C: col=cl, row=(r&3)+8*(r>>2)+4*q) ----
#pragma unroll
    for (int r = 0; r < 16; ++r) {
      int rl = (r & 3) + 8 * (r >> 2) + 4 * q;
      zp[ks * 2208 + rl * 69 + n_t * 32 + cl] = acc[r];
    }
    __syncthreads();

    // ---- reduce + gates: thread (pb, pu); 4 gates = one float4 ----
    float zi = bi, zf = bf_, zg = bg, zo = bo;
#pragma unroll
    for (int k2 = 0; k2 < 4; ++k2) {
      float4 zv = *(const float4*)(zp + k2 * 2208 + pb * 69 + pu * 4);
      zi += zv.x; zf += zv.y; zg += zv.z; zo += zv.w;
    }
    float ig = sigm(zi), fg = sigm(zf), og = sigm(zo);
    float gg = fast_tanh(zg);
    c_reg = fg * c_reg + ig * gg;
    float h = og * fast_tanh(c_reg);
    hstage[(pu >> 3) * 256 + pb * 8 + (pu & 7)] = f2bf(h);
    if (t == T_STEPS - 1) {
      float* orow = out + (size_t)(grp * 32 + pb) * 3072 + j;
      orow[0]    = h;       // h_T
      orow[1024] = h;       // h_T again
      orow[2048] = c_reg;   // c_T
    }
    __syncthreads();              // hstage complete; zp reads done

    // ---- publish h_{t+1} (1KB) + flag: wave 0; release via waitcnt ----
    if (wv == 0) {
      uint32x4 hv = *(const uint32x4*)(hstage + l * 8);
      uint64_t dst = hgrp + (uint64_t)((t + 1) & 1) * 65536 +
                     (uint64_t)nb * 1024 + (uint64_t)l * 16;
      store16_sc(dst, hv);
      WAITV(0);
      if (l == 0) store4_sc(fgrp + (uint64_t)nb * 16, (unsigned)(t + 1));
    }
  }
#undef HMFMA
}

extern "C" void kernel_launch(void* const* d_in, const int* in_sizes, int n_in,
                              void* d_out, int out_size, void* d_ws, size_t ws_size,
                              hipStream_t stream) {
  const float* x = (const float*)d_in[0];
  const float* W = (const float*)d_in[1];
  const float* U = (const float*)d_in[2];
  const float* b = (const float*)d_in[3];
  float* out = (float*)d_out;

  if (ws_size < WS_NEED) return;  // loud failure: output stays poisoned

  u16* xb = (u16*)d_ws;
  // zero h buffers (both groups, both parities) + flags — replayed per launch
  hipMemsetAsync((char*)d_ws + HB_OFF, 0, WS_NEED - HB_OFF, stream);
  cvt_x<<<(T_STEPS * BATCH * DIN / 8 + 255) / 256, 256, 0, stream>>>(x, xb);
  lstm_kernel<<<GRPS * NBG, THREADS, 0, stream>>>(W, U, b, (char*)d_ws, out);
}